// Round 10
// baseline (483.943 us; speedup 1.0000x reference)
//
#include <hip/hip_runtime.h>
#include <hip/hip_bf16.h>

#define NN 100000
#define NE 1200000
#define NE4 (NE / 4)                         // 300000
#define XCD_N 8
#define NPX (NN / XCD_N)                     // 12500 nodes per XCD
#define CAP 32                               // bucket capacity (P(deg>32) ~ 4e-7/node; spill path covers)
#define SPILL_MAX 4096
#define QCAP 22528                           // per (writer,owner) sub-queue entries (mu=18750, +30 sigma)
#define PSPILL_MAX 8192

// ---------------- stage A: edge partition into 8x8 (owner,writer) sub-queues ----------------
// Port law (R9): each XCD's L2-miss port is ~126 GB/s; R6's bucket_fill made every XCD
// stream the whole 9.6MB edge list (~80us). Here blocks read DISJOINT stripes
// (1.2MB/XCD) and append each edge to sub-queue (writer w = blockIdx&7, owner
// q = dst/NPX). Cursor (w,q) and queue lines are written only by XCD w ->
// L2-local, evict once. Cursor atomics are wave-ballot-aggregated (1 atomic per
// queue per 64 edges, own 64B line each).
__global__ __launch_bounds__(256) void part_kernel(const int* __restrict__ esrc,
                                                   const int* __restrict__ edst,
                                                   uint2* __restrict__ queue,
                                                   int* __restrict__ qcur,
                                                   uint2* __restrict__ pspill,
                                                   int* __restrict__ pspill_cnt) {
    int w = blockIdx.x & 7;
    int lane = threadIdx.x & 63;
    unsigned long long lmask = (1ull << lane) - 1;
    for (int i = blockIdx.x * 256 + threadIdx.x; i < NE4; i += gridDim.x * 256) {
        int4 d = ((const int4*)edst)[i];
        int4 s = ((const int4*)esrc)[i];
        #pragma unroll
        for (int c = 0; c < 4; ++c) {
            int dd = (c == 0) ? d.x : (c == 1) ? d.y : (c == 2) ? d.z : d.w;
            int ss = (c == 0) ? s.x : (c == 1) ? s.y : (c == 2) ? s.z : s.w;
            int q = dd / NPX;
            int base = 0;
            #pragma unroll
            for (int qq = 0; qq < 8; ++qq) {          // wave-aggregate cursor atomic per queue
                unsigned long long m = __ballot(q == qq);
                if (m) {
                    int leader = __builtin_ctzll(m);
                    int b = 0;
                    if (lane == leader) b = atomicAdd(&qcur[(w * 8 + qq) * 16], (int)__popcll(m));
                    b = __shfl(b, leader);
                    if (q == qq) base = b + (int)__popcll(m & lmask);
                }
            }
            if (base < QCAP) {
                queue[(size_t)(w * 8 + q) * QCAP + base] = make_uint2((unsigned)dd, (unsigned)ss);
            } else {                                  // ~impossible (+30 sigma); correctness net
                int p = atomicAdd(pspill_cnt, 1);
                if (p < PSPILL_MAX) pspill[p] = make_uint2((unsigned)dd, (unsigned)ss);
            }
        }
    }
}

// ---------------- stage B: owner XCD drains its sub-queues into deg/bucket ----------------
// blocks b: owner q = b&7 (round-robin XCD mapping, normal dispatch only -- R5:
// coop launch breaks it). Reads its 8 sub-queues (~1.2MB/XCD, coalesced);
// deg/bucket lines owned by this XCD (R3/R4 lesson: single-writer-XCD lines).
__global__ __launch_bounds__(256) void fillb_kernel(const uint2* __restrict__ queue,
                                                    const int* __restrict__ qcur,
                                                    const uint2* __restrict__ pspill,
                                                    const int* __restrict__ pspill_cnt,
                                                    int* __restrict__ deg,
                                                    int* __restrict__ bucket,
                                                    int* __restrict__ bspill,
                                                    int* __restrict__ bspill_cnt) {
    int q = blockIdx.x & 7;
    int sub = blockIdx.x >> 3;
    int nsub = gridDim.x >> 3;
    for (int w = 0; w < 8; ++w) {
        int nq = qcur[(w * 8 + q) * 16]; if (nq > QCAP) nq = QCAP;
        const uint2* qp = queue + (size_t)(w * 8 + q) * QCAP;
        for (int j = sub * 256 + threadIdx.x; j < nq; j += nsub * 256) {
            uint2 e = qp[j];
            int slot = atomicAdd(&deg[e.x], 1);
            if (slot < CAP) bucket[e.x * CAP + slot] = (int)e.y;
            else {
                int p = atomicAdd(bspill_cnt, 1);
                if (p < SPILL_MAX) { bspill[2 * p] = (int)e.x; bspill[2 * p + 1] = (int)e.y; }
            }
        }
    }
    // drain stage-A overflow (range-filtered); ~always empty
    int lo = q * NPX;
    int pc = *pspill_cnt; if (pc > PSPILL_MAX) pc = PSPILL_MAX;
    for (int j = sub * 256 + threadIdx.x; j < pc; j += nsub * 256) {
        uint2 e = pspill[j];
        if ((unsigned)((int)e.x - lo) < NPX) {
            int slot = atomicAdd(&deg[e.x], 1);
            if (slot < CAP) bucket[e.x * CAP + slot] = (int)e.y;
            else {
                int p = atomicAdd(bspill_cnt, 1);
                if (p < SPILL_MAX) { bspill[2 * p] = (int)e.x; bspill[2 * p + 1] = (int)e.y; }
            }
        }
    }
}

// ---------------- per-node matmul, self-term folded in ----------------
// MODE 0: t = x[n][f] (f32)
// MODE 1: t = relu(din*(u[n][f] + S[n][f]) + bias[f])   (self u + neighbor-sum S, both bf16)
// writes u'[n] = bf16(din * (t_row @ W)) IN PLACE over u (row-local: block for node n
// only reads row n pre-barrier, writes post-barrier; no cross-node reads).
// POOLADD: also accumulate din*u' into gp (pool's self-term for the final layer).
template <int MODE, int POOLADD>
__global__ __launch_bounds__(256) void mm_kernel(const float* __restrict__ x,
                                                 const __hip_bfloat16* uin,
                                                 const __hip_bfloat16* __restrict__ S,
                                                 const float* __restrict__ W,
                                                 const float* __restrict__ bias,
                                                 const int* __restrict__ deg,
                                                 __hip_bfloat16* uout,
                                                 float* __restrict__ gp) {
    __shared__ float Ws[64 * 64];
    __shared__ float hrow[4][64];
    __shared__ float gpart[64];
    int tid = threadIdx.x;
    {   // stage W (16 KB) via float4
        const float4* Wv = (const float4*)W;
        float4* Wsv = (float4*)Ws;
        #pragma unroll
        for (int i = 0; i < 4; ++i) Wsv[tid + 256 * i] = Wv[tid + 256 * i];
    }
    if (POOLADD && tid < 64) gpart[tid] = 0.f;
    int local = tid >> 6;            // node within block
    int f = tid & 63;                // feature
    int n = blockIdx.x * 4 + local;  // NN divisible by 4
    float din = rsqrtf((float)(deg[n] + 1));
    float v;
    if (MODE == 0) {
        v = x[n * 64 + f];
    } else {
        float uv = __bfloat162float(uin[n * 64 + f]);
        float sv = __bfloat162float(S[n * 64 + f]);
        v = fmaxf(fmaf(din, uv + sv, bias[f]), 0.f);
    }
    hrow[local][f] = v;
    __syncthreads();
    float acc = 0.f;
    #pragma unroll
    for (int k = 0; k < 64; ++k)
        acc = fmaf(hrow[local][k], Ws[k * 64 + f], acc);
    __hip_bfloat16 r = __float2bfloat16(din * acc);
    uout[n * 64 + f] = r;
    if (POOLADD) {                   // pool self-term: gp += din * u'
        atomicAdd(&gpart[f], din * __bfloat162float(r));
        __syncthreads();
        if (tid < 64) atomicAdd(&gp[(blockIdx.x & 63) * 64 + tid], gpart[tid]);
    }
}

// ---------------- neighbor-only aggregation core, G=8 ----------------
// (self-loop moved to mm: removes the 12.8MB u self-stream from this
// port-limited window -- R9 port law: dur ~ per-XCD FETCH / 126 GB/s)
__device__ __forceinline__ void acc_bf8(float acc[8], uint4 v) {
    acc[0] += __uint_as_float(v.x << 16);
    acc[1] += __uint_as_float(v.x & 0xffff0000u);
    acc[2] += __uint_as_float(v.y << 16);
    acc[3] += __uint_as_float(v.y & 0xffff0000u);
    acc[4] += __uint_as_float(v.z << 16);
    acc[5] += __uint_as_float(v.z & 0xffff0000u);
    acc[6] += __uint_as_float(v.w << 16);
    acc[7] += __uint_as_float(v.w & 0xffff0000u);
}

__device__ __forceinline__ unsigned packbf2(float lof, float hif) {
    __hip_bfloat16 l = __float2bfloat16(lof), h = __float2bfloat16(hif);
    unsigned short ul, uh;
    __builtin_memcpy(&ul, &l, 2);
    __builtin_memcpy(&uh, &h, 2);
    return ((unsigned)uh << 16) | ul;
}

// wave = 8 edge-groups x 8 lanes; lane covers features [fo*8,fo*8+8) via one
// dwordx4: one load instruction = 8 x 128B gathers in flight. Bucket row
// batch-loaded once (coalesced) and broadcast by shfl. On exit acc[0..8) =
// neighbor sum, replicated across the 8 groups.
__device__ __forceinline__ void agg_row(const int* __restrict__ degv,
                                        const int* __restrict__ bucket,
                                        const uint4* __restrict__ u4,
                                        const int* __restrict__ bspill,
                                        const int* __restrict__ bspill_cnt,
                                        int n, int lane, int grp, int fo,
                                        float acc[8]) {
    float acc2[8];
    #pragma unroll
    for (int i = 0; i < 8; ++i) { acc[i] = 0.f; acc2[i] = 0.f; }
    int deg = degv[n];
    int dc = deg < CAP ? deg : CAP;
    int cidx = -1;
    if (lane < dc) cidx = bucket[n * CAP + lane];    // one coalesced row load
    int s0 = __shfl(cidx, grp);                      // sweep 0: edges 0..7
    int s1 = __shfl(cidx, grp + 8);                  // sweep 1: edges 8..15
    if (grp < dc) acc_bf8(acc, u4[s0 * 8 + fo]);
    if (grp + 8 < dc) acc_bf8(acc2, u4[s1 * 8 + fo]);
    for (int j = grp + 16; j < dc; j += 8) {         // deg in (16,32]
        int s = __shfl(cidx, j);
        acc_bf8(acc, u4[s * 8 + fo]);
    }
    if (deg > CAP) {                                 // spill drain: ~never taken
        int cnt = *bspill_cnt; if (cnt > SPILL_MAX) cnt = SPILL_MAX;
        for (int e = 0; e < cnt; ++e) {
            if (bspill[2 * e] == n && grp == 0)
                acc_bf8(acc2, u4[bspill[2 * e + 1] * 8 + fo]);
        }
    }
    #pragma unroll
    for (int i = 0; i < 8; ++i) {                    // merge sweeps + 8 groups
        float v = acc[i] + acc2[i];
        v += __shfl_xor(v, 8);
        v += __shfl_xor(v, 16);
        v += __shfl_xor(v, 32);
        acc[i] = v;
    }
}

// ---------------- aggregate (POOL=0: S[n][:]=bf16 neighbor sum; POOL=1: gp += din*S) ----------
// one wave per node, 100000 waves: max TLP, no serial nodes (R1/R2 lesson).
template <int POOL>
__global__ __launch_bounds__(256, 8) void agg_kernel(const int* __restrict__ degv,
                                                     const int* __restrict__ bucket,
                                                     const uint4* __restrict__ uin,
                                                     const int* __restrict__ bspill,
                                                     const int* __restrict__ bspill_cnt,
                                                     __hip_bfloat16* __restrict__ S,
                                                     float* __restrict__ gp) {
    __shared__ float gpart[64];
    int tid = threadIdx.x;
    if (POOL) {
        if (tid < 64) gpart[tid] = 0.f;
        __syncthreads();
    }
    int lane = tid & 63;
    int grp = lane >> 3;
    int fo = lane & 7;
    int n = blockIdx.x * 4 + (tid >> 6);              // NN divisible by 4
    float acc[8];
    agg_row(degv, bucket, uin, bspill, bspill_cnt, n, lane, grp, fo, acc);
    if (POOL) {
        if (grp == 0) {                               // lanes 0..7 hold the full row
            float din = rsqrtf((float)(degv[n] + 1));
            #pragma unroll
            for (int i = 0; i < 8; ++i) atomicAdd(&gpart[fo * 8 + i], din * acc[i]);
        }
        __syncthreads();
        if (tid < 64) atomicAdd(&gp[(blockIdx.x & 63) * 64 + tid], gpart[tid]);
    } else {
        if (grp == 0) {                               // 8 lanes x 16B bf16 = the 128B row
            uint4 pv;
            pv.x = packbf2(acc[0], acc[1]);
            pv.y = packbf2(acc[2], acc[3]);
            pv.z = packbf2(acc[4], acc[5]);
            pv.w = packbf2(acc[6], acc[7]);
            ((uint4*)S)[n * 8 + fo] = pv;
        }
    }
}

// ---------------- head: g = colsum(gp) + N*b2;  out = g @ Wl + bl ----------------
__global__ __launch_bounds__(64) void head_kernel(const float* __restrict__ gp,
                                                  const float* __restrict__ b2,
                                                  const float* __restrict__ Wl,
                                                  const float* __restrict__ bl,
                                                  float* __restrict__ out) {
    int t = threadIdx.x;  // one wave
    float s = 0.f;
    #pragma unroll 8
    for (int r = 0; r < 64; ++r) s += gp[r * 64 + t];
    float gf = s + (float)NN * b2[t];
    #pragma unroll
    for (int c = 0; c < 10; ++c) {
        float p = gf * Wl[t * 10 + c];
        #pragma unroll
        for (int off = 32; off > 0; off >>= 1) p += __shfl_down(p, off);
        if (t == 0) out[c] = p + bl[c];
    }
}

extern "C" void kernel_launch(void* const* d_in, const int* in_sizes, int n_in,
                              void* d_out, int out_size, void* d_ws, size_t ws_size,
                              hipStream_t stream) {
    const float* x  = (const float*)d_in[0];
    const int* eidx = (const int*)d_in[1];
    const int* esrc = eidx;        // edge_idx[0]
    const int* edst = eidx + NE;   // edge_idx[1]
    const float* W0 = (const float*)d_in[2];
    const float* b0 = (const float*)d_in[3];
    const float* W1 = (const float*)d_in[4];
    const float* b1 = (const float*)d_in[5];
    const float* W2 = (const float*)d_in[6];
    const float* b2 = (const float*)d_in[7];
    const float* Wl = (const float*)d_in[8];
    const float* bl = (const float*)d_in[9];
    float* out = (float*)d_out;

    // workspace layout (4-byte units); u/S/queue 16B-aligned (all offsets even)
    float* ws = (float*)d_ws;
    size_t off = 0;
    int*   deg    = (int*)(ws + off); off += NN;
    __hip_bfloat16* u = (__hip_bfloat16*)(ws + off); off += (size_t)NN * 32;  // bf16 N*64
    __hip_bfloat16* S = (__hip_bfloat16*)(ws + off); off += (size_t)NN * 32;  // bf16 N*64
    // control block (one memset): gp + qcur + counters
    float* gp        =        ws + off;  off += 64 * 64;                      // 4096
    int*   qcur      = (int*)(ws + off); off += 64 * 16;                      // 1024 (64B-strided cursors)
    int*   pspill_cnt= (int*)(ws + off); off += 2;
    int*   bspill_cnt= (int*)(ws + off); off += 2;
    size_t ctrl_ints = 4096 + 1024 + 4;
    uint2* pspill = (uint2*)(ws + off); off += 2 * (size_t)PSPILL_MAX;
    int*   bspill = (int*)(ws + off); off += 2 * (size_t)SPILL_MAX;
    uint2* queue  = (uint2*)(ws + off); off += 2 * (size_t)64 * QCAP;         // 11.5 MB
    int*   bucket = (int*)(ws + off); off += (size_t)NN * CAP;                // 12.8 MB

    hipMemsetAsync(deg, 0, NN * sizeof(int), stream);
    hipMemsetAsync(gp, 0, ctrl_ints * sizeof(int), stream);   // gp + qcur + counters

    // two-stage CSR-bucket build (port-law: ~2.4 + ~2.1 MB/XCD vs 9.6 for the one-pass scheme)
    part_kernel<<<2048, 256, 0, stream>>>(esrc, edst, queue, qcur, pspill, pspill_cnt);
    fillb_kernel<<<2048, 256, 0, stream>>>(queue, qcur, pspill, pspill_cnt,
                                           deg, bucket, bspill, bspill_cnt);

    // layer 0: u0 = bf16(din*(x@W0))
    mm_kernel<0, 0><<<NN / 4, 256, 0, stream>>>(x, nullptr, nullptr, W0, nullptr, deg, u, gp);
    // S0 = neighbor sum of u0
    agg_kernel<0><<<NN / 4, 256, 0, stream>>>(deg, bucket, (const uint4*)u, bspill, bspill_cnt, S, gp);
    // layer 1: u1 = bf16(din*(relu(din*(u0+S0)+b0)@W1))   (in-place over u)
    mm_kernel<1, 0><<<NN / 4, 256, 0, stream>>>(nullptr, u, S, W1, b0, deg, u, gp);
    // S1 = neighbor sum of u1 (in-place over S)
    agg_kernel<0><<<NN / 4, 256, 0, stream>>>(deg, bucket, (const uint4*)u, bspill, bspill_cnt, S, gp);
    // layer 2: u2 = ... @W2; also gp += din*u2 (pool self-term)
    mm_kernel<1, 1><<<NN / 4, 256, 0, stream>>>(nullptr, u, S, W2, b1, deg, u, gp);
    // pool neighbor-term: gp += din * S2
    agg_kernel<1><<<NN / 4, 256, 0, stream>>>(deg, bucket, (const uint4*)u, bspill, bspill_cnt, S, gp);
    head_kernel<<<1, 64, 0, stream>>>(gp, b2, Wl, bl, out);
}

// Round 11
// 332.540 us; speedup vs baseline: 1.4553x; 1.4553x over previous
//
#include <hip/hip_runtime.h>
#include <hip/hip_bf16.h>

#define NN 100000
#define NE 1200000
#define NE4 (NE / 4)                         // 300000
#define XCD_N 8
#define NPX (NN / XCD_N)                     // 12500 nodes per XCD
#define CAP 64                               // bucket capacity (P(deg>64) ~ 15 sigma)
#define SPILL_MAX 4096

typedef float floatx2 __attribute__((ext_vector_type(2)));

// ---------------- single-pass CSR-bucket build, XCD-partitioned (R6-proven) ----------------
// block b (XCD = b&7, normal dispatch only -- R5: coop launch breaks this mapping)
// stripes the full edge list with its XCD's sibling blocks and handles only dsts
// in its 12500-node range: deg/bucket lines are written by exactly one XCD ->
// L2-local atomics, dirty lines evict once (R3: 85MB HBM writes without this).
__global__ __launch_bounds__(256) void bucket_fill_kernel(const int* __restrict__ esrc,
                                                          const int* __restrict__ edst,
                                                          int* __restrict__ deg,
                                                          int* __restrict__ bucket,
                                                          int* __restrict__ spill,
                                                          int* __restrict__ spill_cnt) {
    int xcd = blockIdx.x & 7;
    int sub = blockIdx.x >> 3;
    int nsub = gridDim.x >> 3;
    int lo = xcd * NPX;
    for (int i = sub * 256 + threadIdx.x; i < NE4; i += nsub * 256) {
        int4 d  = ((const int4*)edst)[i];
        int4 sr = ((const int4*)esrc)[i];
        #pragma unroll
        for (int c = 0; c < 4; ++c) {
            int dd = (c == 0) ? d.x : (c == 1) ? d.y : (c == 2) ? d.z : d.w;
            int ss = (c == 0) ? sr.x : (c == 1) ? sr.y : (c == 2) ? sr.z : sr.w;
            if ((unsigned)(dd - lo) < NPX) {
                int slot = atomicAdd(&deg[dd], 1);
                if (slot < CAP) {
                    bucket[dd * CAP + slot] = ss;
                } else {
                    int p = atomicAdd(spill_cnt, 1);
                    if (p < SPILL_MAX) { spill[2 * p] = dd; spill[2 * p + 1] = ss; }
                }
            }
        }
    }
}

// ---------------- fp8 e4m3 encode/decode via HW cvt (gfx950) ----------------
__device__ __forceinline__ unsigned char enc_fp8(float f) {
    int w = __builtin_amdgcn_cvt_pk_fp8_f32(f, f, 0, false);
    return (unsigned char)(w & 0xFF);
}

// decode 8 fp8 (one uint2 = 8 bytes = lane's feature octet) and accumulate
__device__ __forceinline__ void acc_fp8(float acc[8], uint2 v) {
    floatx2 a0 = __builtin_amdgcn_cvt_pk_f32_fp8((int)v.x, false);
    floatx2 a1 = __builtin_amdgcn_cvt_pk_f32_fp8((int)v.x, true);
    floatx2 a2 = __builtin_amdgcn_cvt_pk_f32_fp8((int)v.y, false);
    floatx2 a3 = __builtin_amdgcn_cvt_pk_f32_fp8((int)v.y, true);
    acc[0] += a0.x; acc[1] += a0.y;
    acc[2] += a1.x; acc[3] += a1.y;
    acc[4] += a2.x; acc[5] += a2.y;
    acc[6] += a3.x; acc[7] += a3.y;
}

// ---------------- layer-0 matmul: u8 = fp8(din * (x @ W0)) ----------------
__global__ __launch_bounds__(256) void mm0_kernel(const float* __restrict__ in,
                                                  const float* __restrict__ W,
                                                  const int* __restrict__ deg,
                                                  unsigned char* __restrict__ u8) {
    __shared__ float Ws[64 * 64];
    __shared__ float hrow[4][64];
    int tid = threadIdx.x;
    {   // stage W (16 KB) via float4
        const float4* Wv = (const float4*)W;
        float4* Wsv = (float4*)Ws;
        #pragma unroll
        for (int i = 0; i < 4; ++i) Wsv[tid + 256 * i] = Wv[tid + 256 * i];
    }
    int local = tid >> 6;            // node within block
    int f = tid & 63;                // feature
    int n = blockIdx.x * 4 + local;  // NN divisible by 4
    float din = rsqrtf((float)(deg[n] + 1));
    hrow[local][f] = in[n * 64 + f];
    __syncthreads();
    float acc = 0.f;
    #pragma unroll
    for (int k = 0; k < 64; ++k)
        acc = fmaf(hrow[local][k], Ws[k * 64 + f], acc);
    u8[n * 64 + f] = enc_fp8(din * acc);
}

// ---------------- aggregation core, G=8 over fp8 rows ----------------
// wave = 8 edge-groups x 8 lanes; lane covers features [fo*8,fo*8+8) via one
// dwordx2 (8B of fp8): per edge, 8 lanes span the 64B row = EXACTLY ONE cache
// line (vs 2 for bf16 -- the R9 port law says dur ~ per-XCD miss-bytes/126GB/s,
// so halving gather lines halves the floor). Bucket row batch-loaded once
// (coalesced) and broadcast by shfl. On exit acc[0..8) = aggregated row
// (self + neighbors), replicated across the 8 groups.
__device__ __forceinline__ void agg_row(const int* __restrict__ degv,
                                        const int* __restrict__ bucket,
                                        const uint2* __restrict__ u2,
                                        const int* __restrict__ spill,
                                        const int* __restrict__ spill_cnt,
                                        int n, int lane, int grp, int fo,
                                        float acc[8]) {
    float acc2[8];
    #pragma unroll
    for (int i = 0; i < 8; ++i) { acc[i] = 0.f; acc2[i] = 0.f; }
    int deg = degv[n];
    int dc = deg < CAP ? deg : CAP;
    int cidx = -1;
    if (lane < dc) cidx = bucket[n * CAP + lane];    // one coalesced row load
    if (grp == 0) acc_fp8(acc, u2[n * 8 + fo]);      // self loop
    int s0 = __shfl(cidx, grp);                      // sweep 0: edges 0..7
    int s1 = __shfl(cidx, grp + 8);                  // sweep 1: edges 8..15
    if (grp < dc) acc_fp8(acc, u2[s0 * 8 + fo]);
    if (grp + 8 < dc) acc_fp8(acc2, u2[s1 * 8 + fo]);
    for (int j = grp + 16; j < dc; j += 8) {         // deg in (16,64]
        int s = __shfl(cidx, j);
        acc_fp8(acc, u2[s * 8 + fo]);
    }
    if (deg > CAP) {                                 // spill drain: ~never taken
        int cnt = *spill_cnt; if (cnt > SPILL_MAX) cnt = SPILL_MAX;
        for (int e = 0; e < cnt; ++e) {
            if (spill[2 * e] == n && grp == 0)
                acc_fp8(acc2, u2[spill[2 * e + 1] * 8 + fo]);
        }
    }
    #pragma unroll
    for (int i = 0; i < 8; ++i) {                    // merge sweeps + 8 groups
        float v = acc[i] + acc2[i];
        v += __shfl_xor(v, 8);
        v += __shfl_xor(v, 16);
        v += __shfl_xor(v, 32);
        acc[i] = v;
    }
}

// ---------------- fused aggregate + finalize + next-layer matmul (R7-proven) ----------------
// per node n (one wave, 100000 waves -- R1/R2 lesson: never serialize nodes):
//   acc = u[n] + sum_{src} u[src]                       (gather, port-floor bound)
//   t   = relu(din*acc + bias)                          (finalize prev layer)
//   uout[n] = fp8( din * (t @ W) )                      (LDS-broadcast matmul)
__global__ __launch_bounds__(256, 6) void aggmm_kernel(const int* __restrict__ degv,
                                                       const int* __restrict__ bucket,
                                                       const uint2* __restrict__ uin,
                                                       const int* __restrict__ spill,
                                                       const int* __restrict__ spill_cnt,
                                                       const float* __restrict__ bias,
                                                       const float* __restrict__ W,
                                                       unsigned char* __restrict__ uout) {
    __shared__ float Ws[64 * 64];
    __shared__ float hrow[4][64];
    int tid = threadIdx.x;
    {   // stage W (16 KB) via float4
        const float4* Wv = (const float4*)W;
        float4* Wsv = (float4*)Ws;
        #pragma unroll
        for (int i = 0; i < 4; ++i) Wsv[tid + 256 * i] = Wv[tid + 256 * i];
    }
    __syncthreads();
    int wid = tid >> 6;
    int lane = tid & 63;
    int grp = lane >> 3;
    int fo = lane & 7;
    int n = blockIdx.x * 4 + wid;                     // NN divisible by 4
    float acc[8];
    agg_row(degv, bucket, uin, spill, spill_cnt, n, lane, grp, fo, acc);
    float din = rsqrtf((float)(degv[n] + 1));
    if (grp == 0) {                                   // lanes 0..7 hold the full row
        float4 blo = ((const float4*)bias)[fo * 2];
        float4 bhi = ((const float4*)bias)[fo * 2 + 1];
        float4 lo, hi;
        lo.x = fmaxf(fmaf(din, acc[0], blo.x), 0.f);
        lo.y = fmaxf(fmaf(din, acc[1], blo.y), 0.f);
        lo.z = fmaxf(fmaf(din, acc[2], blo.z), 0.f);
        lo.w = fmaxf(fmaf(din, acc[3], blo.w), 0.f);
        hi.x = fmaxf(fmaf(din, acc[4], bhi.x), 0.f);
        hi.y = fmaxf(fmaf(din, acc[5], bhi.y), 0.f);
        hi.z = fmaxf(fmaf(din, acc[6], bhi.z), 0.f);
        hi.w = fmaxf(fmaf(din, acc[7], bhi.w), 0.f);
        ((float4*)hrow[wid])[fo * 2] = lo;            // t row -> per-wave LDS
        ((float4*)hrow[wid])[fo * 2 + 1] = hi;
    }
    // same-wave LDS RAW (write above, read below): in-order LDS + compiler
    // lgkmcnt ordering through the shared array; no barrier needed (R7-proven).
    float o = 0.f;
    const float4* hv = (const float4*)hrow[wid];
    #pragma unroll
    for (int k4 = 0; k4 < 16; ++k4) {
        float4 h = hv[k4];                            // broadcast read (all lanes same addr)
        int kb = k4 * 4;
        o = fmaf(h.x, Ws[(kb + 0) * 64 + lane], o);
        o = fmaf(h.y, Ws[(kb + 1) * 64 + lane], o);
        o = fmaf(h.z, Ws[(kb + 2) * 64 + lane], o);
        o = fmaf(h.w, Ws[(kb + 3) * 64 + lane], o);
    }
    uout[n * 64 + lane] = enc_fp8(din * o);
}

// ---------------- final aggregate + global pool: gp += din*agg ----------------
__global__ __launch_bounds__(256, 6) void aggpool_kernel(const int* __restrict__ degv,
                                                         const int* __restrict__ bucket,
                                                         const uint2* __restrict__ uin,
                                                         const int* __restrict__ spill,
                                                         const int* __restrict__ spill_cnt,
                                                         float* __restrict__ gp) {
    __shared__ float gpart[64];
    int tid = threadIdx.x;
    if (tid < 64) gpart[tid] = 0.f;
    __syncthreads();
    int lane = tid & 63;
    int grp = lane >> 3;
    int fo = lane & 7;
    int n = blockIdx.x * 4 + (tid >> 6);              // NN divisible by 4
    float acc[8];
    agg_row(degv, bucket, uin, spill, spill_cnt, n, lane, grp, fo, acc);
    if (grp == 0) {                                   // lanes 0..7 hold the full row
        float din = rsqrtf((float)(degv[n] + 1));
        #pragma unroll
        for (int i = 0; i < 8; ++i) atomicAdd(&gpart[fo * 8 + i], din * acc[i]);
    }
    __syncthreads();
    if (tid < 64) atomicAdd(&gp[(blockIdx.x & 63) * 64 + tid], gpart[tid]);
}

// ---------------- head: g = colsum(gp) + N*b2;  out = g @ Wl + bl ----------------
__global__ __launch_bounds__(64) void head_kernel(const float* __restrict__ gp,
                                                  const float* __restrict__ b2,
                                                  const float* __restrict__ Wl,
                                                  const float* __restrict__ bl,
                                                  float* __restrict__ out) {
    int t = threadIdx.x;  // one wave
    float s = 0.f;
    #pragma unroll 8
    for (int r = 0; r < 64; ++r) s += gp[r * 64 + t];
    float gf = s + (float)NN * b2[t];
    #pragma unroll
    for (int c = 0; c < 10; ++c) {
        float p = gf * Wl[t * 10 + c];
        #pragma unroll
        for (int off = 32; off > 0; off >>= 1) p += __shfl_down(p, off);
        if (t == 0) out[c] = p + bl[c];
    }
}

extern "C" void kernel_launch(void* const* d_in, const int* in_sizes, int n_in,
                              void* d_out, int out_size, void* d_ws, size_t ws_size,
                              hipStream_t stream) {
    const float* x  = (const float*)d_in[0];
    const int* eidx = (const int*)d_in[1];
    const int* esrc = eidx;        // edge_idx[0]
    const int* edst = eidx + NE;   // edge_idx[1]
    const float* W0 = (const float*)d_in[2];
    const float* b0 = (const float*)d_in[3];
    const float* W1 = (const float*)d_in[4];
    const float* b1 = (const float*)d_in[5];
    const float* W2 = (const float*)d_in[6];
    const float* b2 = (const float*)d_in[7];
    const float* Wl = (const float*)d_in[8];
    const float* bl = (const float*)d_in[9];
    float* out = (float*)d_out;

    // workspace layout (4-byte units); ua/ub 8B-aligned for uint2 gathers
    float* ws = (float*)d_ws;
    size_t off = 0;
    int*   deg    = (int*)(ws + off); off += NN;
    unsigned char* ua = (unsigned char*)(ws + off); off += (size_t)NN * 16;   // fp8 N*64 (6.4MB)
    unsigned char* ub = (unsigned char*)(ws + off); off += (size_t)NN * 16;   // fp8 N*64
    float* gp     =        ws + off;  off += 64 * 64;                          // pool partials
    int*   spill_cnt = (int*)(ws + off); off += 4;                             // adjacent to gp: one memset
    int*   spill  = (int*)(ws + off); off += 2 * SPILL_MAX;
    int*   bucket = (int*)(ws + off); off += (size_t)NN * CAP;                 // 25.6 MB

    hipMemsetAsync(deg, 0, NN * sizeof(int), stream);
    hipMemsetAsync(gp, 0, (64 * 64 + 4) * sizeof(float), stream);  // gp + spill_cnt

    // single-pass bucket CSR build (normal dispatch: R5 proved coop launch breaks b&7->XCD)
    bucket_fill_kernel<<<2048, 256, 0, stream>>>(esrc, edst, deg, bucket, spill, spill_cnt);

    // layer 0 matmul: ua = fp8(din*(x@W0))
    mm0_kernel<<<NN / 4, 256, 0, stream>>>(x, W0, deg, ua);
    // fused: agg(ua) + relu/bias(b0) + matmul(W1) -> ub
    aggmm_kernel<<<NN / 4, 256, 0, stream>>>(deg, bucket, (const uint2*)ua, spill, spill_cnt, b0, W1, ub);
    // fused: agg(ub) + relu/bias(b1) + matmul(W2) -> ua
    aggmm_kernel<<<NN / 4, 256, 0, stream>>>(deg, bucket, (const uint2*)ub, spill, spill_cnt, b1, W2, ua);
    // fused: agg(ua) + global pool (din folded; N*b2 added in head)
    aggpool_kernel<<<NN / 4, 256, 0, stream>>>(deg, bucket, (const uint2*)ua, spill, spill_cnt, gp);
    head_kernel<<<1, 64, 0, stream>>>(gp, b2, Wl, bl, out);
}